// Round 19
// baseline (884.902 us; speedup 1.0000x reference)
//
#include <hip/hip_runtime.h>
#include <hip/hip_bf16.h>

typedef __attribute__((ext_vector_type(8))) short short8;
typedef __attribute__((ext_vector_type(4))) float f32x4;
typedef __attribute__((ext_vector_type(4))) unsigned short ushort4v;

static __device__ __forceinline__ unsigned short f2bf(float f) {
  unsigned u = __float_as_uint(f);
  unsigned r = (u + 0x7fffu + ((u >> 16) & 1u)) >> 16;
  return (unsigned short)r;
}
// library cvt (RNE): compiler can emit v_cvt_pk_bf16_f32 pairs (m240)
static __device__ __forceinline__ unsigned short f2bf_fast(float f) {
  __hip_bfloat16 h = __float2bfloat16(f);
  return *reinterpret_cast<unsigned short*>(&h);
}
static __device__ __forceinline__ short8 pack8(float4 a, float4 b) {
  short8 r;
  r[0] = (short)f2bf_fast(a.x); r[1] = (short)f2bf_fast(a.y);
  r[2] = (short)f2bf_fast(a.z); r[3] = (short)f2bf_fast(a.w);
  r[4] = (short)f2bf_fast(b.x); r[5] = (short)f2bf_fast(b.y);
  r[6] = (short)f2bf_fast(b.z); r[7] = (short)f2bf_fast(b.w);
  return r;
}

// DPP-based max over each 16-lane group (all lanes receive the result).
template <int CTRL>
static __device__ __forceinline__ float fmax_dpp(float x) {
  int t = __builtin_amdgcn_update_dpp(__float_as_int(x), __float_as_int(x),
                                      CTRL, 0xF, 0xF, true);
  return fmaxf(x, __int_as_float(t));
}
static __device__ __forceinline__ float max16_dpp(float x) {
  x = fmax_dpp<0xB1>(x);   // quad_perm xor1
  x = fmax_dpp<0x4E>(x);   // quad_perm xor2
  x = fmax_dpp<0x141>(x);  // row_half_mirror
  x = fmax_dpp<0x140>(x);  // row_mirror
  return x;
}

// ---------------------------------------------------------------------------
// weights fp32 -> bf16 (4 x 768x768). grid (576, 4), 256 thr.
// ---------------------------------------------------------------------------
__global__ __launch_bounds__(256) void cvt_w4(
    const float* __restrict__ w0, const float* __restrict__ w1,
    const float* __restrict__ w2, const float* __restrict__ w3,
    unsigned short* __restrict__ o)
{
  const int z = blockIdx.y;
  const float* src = (z == 0) ? w0 : (z == 1) ? w1 : (z == 2) ? w2 : w3;
  unsigned short* dst = o + (size_t)z * 589824;
  const int i = blockIdx.x * 256 + threadIdx.x;  // exact: 576*256 = 147456
  float4 f = ((const float4*)src)[i];
  ushort4v v;
  v[0] = f2bf_fast(f.x); v[1] = f2bf_fast(f.y);
  v[2] = f2bf_fast(f.z); v[3] = f2bf_fast(f.w);
  ((ushort4v*)dst)[i] = v;
}

// ---------------------------------------------------------------------------
// 128x128-tile GEMM (r18, unchanged). A fp32->bf16 in regs or bf16; B bf16.
// ---------------------------------------------------------------------------
template<int XF32, int OUTF32>
__device__ __forceinline__ void gemm128(
    const void* Xp, const unsigned short* Wb, const float* bias,
    void* outp, float scale, int vt_mode, int bm, int bn)
{
  __shared__ unsigned short Als[128 * 32];
  __shared__ unsigned short Bls[128 * 32];

  const int tid = threadIdx.x;
  const int wave = tid >> 6, lane = tid & 63;
  const int g = lane >> 4, lo = lane & 15;
  const int wr = wave >> 1, wc = wave & 1;
  const int m0 = bm * 128, n0 = bn * 128;

  const f32x4 vzero = {0.f, 0.f, 0.f, 0.f};
  f32x4 acc[4][4];
#pragma unroll
  for (int m = 0; m < 4; ++m)
#pragma unroll
    for (int n = 0; n < 4; ++n) acc[m][n] = vzero;

  const int arow = tid >> 1;        // 0..127
  const int acol = (tid & 1) * 16;  // 0 or 16
  const float* Af = nullptr;
  const unsigned short* Ab = nullptr;
  if constexpr (XF32) Af = (const float*)Xp + (size_t)(m0 + arow) * 768 + acol;
  else                Ab = (const unsigned short*)Xp + (size_t)(m0 + arow) * 768 + acol;
  const unsigned short* Brow = Wb + (size_t)(n0 + arow) * 768 + acol;

  for (int k0 = 0; k0 < 768; k0 += 32) {
    short8 va0, va1;
    if constexpr (XF32) {
      float4 f0 = *(const float4*)(Af + k0);
      float4 f1 = *(const float4*)(Af + k0 + 4);
      float4 f2 = *(const float4*)(Af + k0 + 8);
      float4 f3 = *(const float4*)(Af + k0 + 12);
      va0 = pack8(f0, f1);
      va1 = pack8(f2, f3);
    } else {
      va0 = *(const short8*)(Ab + k0);
      va1 = *(const short8*)(Ab + k0 + 8);
    }
    short8 vb0 = *(const short8*)(Brow + k0);
    short8 vb1 = *(const short8*)(Brow + k0 + 8);

    __syncthreads();  // previous tile fully consumed
    *(short8*)(Als + arow * 32 + acol)     = va0;
    *(short8*)(Als + arow * 32 + acol + 8) = va1;
    *(short8*)(Bls + arow * 32 + acol)     = vb0;
    *(short8*)(Bls + arow * 32 + acol + 8) = vb1;
    __syncthreads();  // tile visible

    short8 af[4], bf[4];
#pragma unroll
    for (int m = 0; m < 4; ++m)
      af[m] = *(const short8*)(Als + (wr * 64 + m * 16 + lo) * 32 + g * 8);
#pragma unroll
    for (int n = 0; n < 4; ++n)
      bf[n] = *(const short8*)(Bls + (wc * 64 + n * 16 + lo) * 32 + g * 8);
#pragma unroll
    for (int m = 0; m < 4; ++m)
#pragma unroll
      for (int n = 0; n < 4; ++n)
        acc[m][n] = __builtin_amdgcn_mfma_f32_16x16x32_bf16(af[m], bf[n], acc[m][n], 0, 0, 0);
  }

#pragma unroll
  for (int n = 0; n < 4; ++n) {
    const int ncol = n0 + wc * 64 + n * 16 + lo;
    const float bb = bias[ncol];
#pragma unroll
    for (int m = 0; m < 4; ++m) {
      const int rowb = m0 + wr * 64 + m * 16 + g * 4;
      if constexpr (OUTF32) {
        float* out = (float*)outp;
#pragma unroll
        for (int r = 0; r < 4; ++r)
          out[(size_t)(rowb + r) * 768 + ncol] = (acc[m][n][r] + bb) * scale;
      } else {
        unsigned short* out = (unsigned short*)outp;
        if (!vt_mode) {
#pragma unroll
          for (int r = 0; r < 4; ++r)
            out[(size_t)(rowb + r) * 768 + ncol] = f2bf((acc[m][n][r] + bb) * scale);
        } else {
          const int b = rowb >> 12, s = rowb & 4095;
          const int hh = ncol >> 6, d = ncol & 63;
          ushort4v pk;
#pragma unroll
          for (int r = 0; r < 4; ++r) pk[r] = f2bf((acc[m][n][r] + bb) * scale);
          *(ushort4v*)(out + (((size_t)b * 12 + hh) * 64 + d) * 4096 + s) = pk;
        }
      }
    }
  }
}

__global__ __launch_bounds__(256, 2) void qkv_proj(
    const float* __restrict__ Qi, const float* __restrict__ Ki,
    const float* __restrict__ Vi,
    const unsigned short* __restrict__ Wq, const float* __restrict__ bq,
    const unsigned short* __restrict__ Wk, const float* __restrict__ bk,
    const unsigned short* __restrict__ Wv, const float* __restrict__ bv,
    unsigned short* __restrict__ qo, unsigned short* __restrict__ ko,
    unsigned short* __restrict__ vto)
{
  const int z = blockIdx.z;
  const float* X = (z == 0) ? Qi : (z == 1) ? Ki : Vi;
  const unsigned short* W = (z == 0) ? Wq : (z == 1) ? Wk : Wv;
  const float* bb = (z == 0) ? bq : (z == 1) ? bk : bv;
  unsigned short* out = (z == 0) ? qo : (z == 1) ? ko : vto;
  // q gets 1/sqrt(dk) * log2(e) so softmax runs in exp2 domain
  const float scale = (z == 0) ? 0.18033688011f : 1.0f;
  gemm128<1, 0>(X, W, bb, out, scale, (z == 2) ? 1 : 0, blockIdx.x, blockIdx.y);
}

__global__ __launch_bounds__(256, 2) void out_proj(
    const unsigned short* __restrict__ X, const unsigned short* __restrict__ W,
    const float* __restrict__ bias, float* __restrict__ out)
{
  gemm128<0, 1>(X, W, bias, out, 1.0f, 0, blockIdx.x, blockIdx.y);
}

// ---------------------------------------------------------------------------
// Flash attention v11 = r8/r18 structure with V staging DROPPED
// (Common-mistake #7 / m169: don't LDS-stage L2-resident data; each head's
// V^T slice is 512 KB, reused by 32 blocks x 8 waves). PV B-fragments read
// directly from global V^T (natural 16B/lane chunks); depth-2 register
// pipeline (nd 0,1 issued before softmax, 2,3 interleaved) hides L2 latency.
// LDS drops 34.8 -> 26.6 KB (K 8K + P 18.4K); ~40% less LDS traffic.
// Everything else identical to r18's attn (183-200 us band).
// ---------------------------------------------------------------------------
__global__ __launch_bounds__(512, 6) void attn_fwd(
    const unsigned short* qw, const unsigned short* __restrict__ kw,
    const unsigned short* __restrict__ vtw, unsigned short* ow)
{
  __shared__ unsigned short Kls[64 * 64];
  __shared__ unsigned short Pls[8 * 16 * 72];  // per-wave [16][72]

  const int tid = threadIdx.x, wave = tid >> 6, lane = tid & 63;
  const int g = lane >> 4, lo = lane & 15;
  const int bh = blockIdx.y, b = bh / 12, hh = bh % 12;
  const int q0 = blockIdx.x * 128 + wave * 16;

  // Q A-fragments: rows q0+lo, k-dims s*32+g*8..+7
  short8 aq[2];
#pragma unroll
  for (int s = 0; s < 2; ++s)
    aq[s] = *(const short8*)(qw + (size_t)(b * 4096 + q0 + lo) * 768
                             + hh * 64 + s * 32 + g * 8);

  const f32x4 vzero = {0.f, 0.f, 0.f, 0.f};
  float mx[4];
  f32x4 lacc = vzero;   // row-sum accumulator via ones-MFMA
  f32x4 oacc[4];
#pragma unroll
  for (int r = 0; r < 4; ++r) mx[r] = -1e30f;
#pragma unroll
  for (int n = 0; n < 4; ++n) oacc[n] = vzero;

  short8 bone;  // B-fragment of bf16 1.0 -> D[row][*] = row-sum of A
#pragma unroll
  for (int j = 0; j < 8; ++j) bone[j] = (short)0x3F80;

  unsigned short* Pw = Pls + wave * (16 * 72);
  char* Kb = (char*)Kls;

  // K staging: 512 threads cover 64 rows x 8 x 16B chunks (1 chunk each)
  const int srow = tid >> 3;
  const int sc = tid & 7;
  const unsigned short* krow = kw + ((size_t)b * 4096 + srow) * 768 + hh * 64 + sc * 8;
  const int sdst = srow * 128 + ((sc * 16) ^ ((srow & 7) << 4));

  // V fragment global base: row nd*16+lo of V^T -> +nd*65536; cols kv0+g*8(+32)
  const unsigned short* vbase = vtw + ((size_t)bh * 64 + lo) * 4096 + g * 8;

  // prefetch K tile 0
  short8 kl = *(const short8*)(krow);

  for (int kv0 = 0; kv0 < 4096; kv0 += 64) {
    // WAR: all waves done reading previous tile's LDS. Raw barrier: does NOT
    // drain vmcnt, so the prefetched loads stay in flight.
    asm volatile("s_waitcnt lgkmcnt(0)" ::: "memory");
    __builtin_amdgcn_s_barrier();
    *(short8*)(Kb + sdst) = kl;   // compiler inserts vmcnt wait (data dep)
    if (kv0 + 64 < 4096) {        // prefetch next K tile
      kl = *(const short8*)(krow + (size_t)(kv0 + 64) * 768);
    }
    asm volatile("s_waitcnt lgkmcnt(0)" ::: "memory");  // my write visible
    __builtin_amdgcn_s_barrier();                       // all writes visible
    __builtin_amdgcn_sched_barrier(0);                  // pin: no hoist above

    // ---- S = q @ k^T (exp2-domain scale folded into q) ----
    f32x4 sa[4];
#pragma unroll
    for (int n = 0; n < 4; ++n) {
      const int row = n * 16 + lo;
      const int rsw = (row & 7) << 4;
      short8 bk0 = *(const short8*)(Kb + row * 128 + ((g * 16) ^ rsw));
      short8 bk1 = *(const short8*)(Kb + row * 128 + ((64 + g * 16) ^ rsw));
      f32x4 t = vzero;
      t = __builtin_amdgcn_mfma_f32_16x16x32_bf16(aq[0], bk0, t, 0, 0, 0);
      t = __builtin_amdgcn_mfma_f32_16x16x32_bf16(aq[1], bk1, t, 0, 0, 0);
      sa[n] = t;
    }

    // ---- V prefetch nd=0,1 from L2 (latency hidden under softmax) ----
    short8 vA0 = *(const short8*)(vbase + kv0);
    short8 vA1 = *(const short8*)(vbase + kv0 + 32);
    short8 vB0 = *(const short8*)(vbase + 65536 + kv0);
    short8 vB1 = *(const short8*)(vbase + 65536 + kv0 + 32);

    // ---- online softmax (row = g*4 + r, cols = n*16 + lo) ----
#pragma unroll
    for (int r = 0; r < 4; ++r) {
      float pm = fmaxf(fmaxf(sa[0][r], sa[1][r]), fmaxf(sa[2][r], sa[3][r]));
      pm = max16_dpp(pm);
      if (pm > mx[r] + 8.f) {  // defer-max: rescale only on big max growth
        const float fr = __builtin_amdgcn_exp2f(mx[r] - pm);  // 1st tile: 0
        mx[r] = pm;
        lacc[r] *= fr;
#pragma unroll
        for (int nd = 0; nd < 4; ++nd) oacc[nd][r] *= fr;
      }
#pragma unroll
      for (int n = 0; n < 4; ++n) {
        const float pv = __builtin_amdgcn_exp2f(sa[n][r] - mx[r]);
        // truncating bf16 store: fuses to ds_write_b16_d16_hi (0 VALU rounding)
        *(unsigned short*)((char*)Pw + (g * 4 + r) * 144 + n * 32 + lo * 2) =
            (unsigned short)(__float_as_uint(pv) >> 16);
      }
    }

    // ---- O += P @ V (depth-2 V pipeline) ; l += P @ 1 ----
    short8 ap0 = *(const short8*)((char*)Pw + lo * 144 + g * 16);
    short8 ap1 = *(const short8*)((char*)Pw + lo * 144 + 64 + g * 16);

    oacc[0] = __builtin_amdgcn_mfma_f32_16x16x32_bf16(ap0, vA0, oacc[0], 0, 0, 0);
    oacc[0] = __builtin_amdgcn_mfma_f32_16x16x32_bf16(ap1, vA1, oacc[0], 0, 0, 0);
    vA0 = *(const short8*)(vbase + 2 * 65536 + kv0);        // nd=2
    vA1 = *(const short8*)(vbase + 2 * 65536 + kv0 + 32);

    oacc[1] = __builtin_amdgcn_mfma_f32_16x16x32_bf16(ap0, vB0, oacc[1], 0, 0, 0);
    oacc[1] = __builtin_amdgcn_mfma_f32_16x16x32_bf16(ap1, vB1, oacc[1], 0, 0, 0);
    vB0 = *(const short8*)(vbase + 3 * 65536 + kv0);        // nd=3
    vB1 = *(const short8*)(vbase + 3 * 65536 + kv0 + 32);

    lacc = __builtin_amdgcn_mfma_f32_16x16x32_bf16(ap0, bone, lacc, 0, 0, 0);
    lacc = __builtin_amdgcn_mfma_f32_16x16x32_bf16(ap1, bone, lacc, 0, 0, 0);

    oacc[2] = __builtin_amdgcn_mfma_f32_16x16x32_bf16(ap0, vA0, oacc[2], 0, 0, 0);
    oacc[2] = __builtin_amdgcn_mfma_f32_16x16x32_bf16(ap1, vA1, oacc[2], 0, 0, 0);
    oacc[3] = __builtin_amdgcn_mfma_f32_16x16x32_bf16(ap0, vB0, oacc[3], 0, 0, 0);
    oacc[3] = __builtin_amdgcn_mfma_f32_16x16x32_bf16(ap1, vB1, oacc[3], 0, 0, 0);
  }

  // epilogue: normalize (RNE), store merged-head bf16 [8192][768] (in-place ok)
#pragma unroll
  for (int r = 0; r < 4; ++r) {
    const float inv = 1.f / lacc[r];
    const size_t rowoff = (size_t)(b * 4096 + q0 + g * 4 + r) * 768 + hh * 64;
#pragma unroll
    for (int nd = 0; nd < 4; ++nd)
      ow[rowoff + nd * 16 + lo] = f2bf(oacc[nd][r] * inv);
  }
}

extern "C" void kernel_launch(void* const* d_in, const int* in_sizes, int n_in,
                              void* d_out, int out_size, void* d_ws, size_t ws_size,
                              hipStream_t stream) {
  (void)in_sizes; (void)n_in; (void)out_size; (void)ws_size;
  const float* Qi = (const float*)d_in[0];
  const float* Ki = (const float*)d_in[1];
  const float* Vi = (const float*)d_in[2];
  const float* Wq = (const float*)d_in[3];
  const float* bq = (const float*)d_in[4];
  const float* Wk = (const float*)d_in[5];
  const float* bk = (const float*)d_in[6];
  const float* Wv = (const float*)d_in[7];
  const float* bv = (const float*)d_in[8];
  const float* Wo = (const float*)d_in[9];
  const float* bo = (const float*)d_in[10];

  // ws: q bf16 + v^T bf16 (25.2 MB) + 4 bf16 weights (4.7 MB).
  // k bf16 scratch lives in d_out's first 12.6 MB (overwritten by out_proj's
  // fp32 output at the very end, stream-ordered). Attn output in-place in qw.
  unsigned short* ws = (unsigned short*)d_ws;
  const size_t NTOK = 8192u * 768u;  // 6291456
  const size_t NW = 589824;          // 768*768
  unsigned short* qw  = ws;
  unsigned short* vtw = ws + NTOK;
  unsigned short* wbf = ws + 2 * NTOK;
  unsigned short* Wqc = wbf;
  unsigned short* Wkc = wbf + NW;
  unsigned short* Wvc = wbf + 2 * NW;
  unsigned short* Woc = wbf + 3 * NW;
  unsigned short* kwp = (unsigned short*)d_out;

  cvt_w4<<<dim3(576, 4), 256, 0, stream>>>(Wq, Wk, Wv, Wo, wbf);
  qkv_proj<<<dim3(64, 6, 3), 256, 0, stream>>>(Qi, Ki, Vi, Wqc, bq, Wkc, bk,
                                               Wvc, bv, qw, kwp, vtw);
  attn_fwd<<<dim3(32, 24, 1), 512, 0, stream>>>(qw, kwp, vtw, qw);
  out_proj<<<dim3(64, 6, 1), 256, 0, stream>>>(qw, Woc, bo, (float*)d_out);
}

// Round 20
// 251.226 us; speedup vs baseline: 3.5223x; 3.5223x over previous
//
#include <hip/hip_runtime.h>
#include <hip/hip_bf16.h>

typedef __attribute__((ext_vector_type(8))) short short8;
typedef __attribute__((ext_vector_type(4))) float f32x4;
typedef __attribute__((ext_vector_type(4))) unsigned short ushort4v;

static __device__ __forceinline__ unsigned short f2bf(float f) {
  unsigned u = __float_as_uint(f);
  unsigned r = (u + 0x7fffu + ((u >> 16) & 1u)) >> 16;
  return (unsigned short)r;
}
// library cvt (RNE): compiler emits v_cvt_pk_bf16_f32 pairs (m240)
static __device__ __forceinline__ unsigned short f2bf_fast(float f) {
  __hip_bfloat16 h = __float2bfloat16(f);
  return *reinterpret_cast<unsigned short*>(&h);
}
static __device__ __forceinline__ short8 pack8(float4 a, float4 b) {
  short8 r;
  r[0] = (short)f2bf_fast(a.x); r[1] = (short)f2bf_fast(a.y);
  r[2] = (short)f2bf_fast(a.z); r[3] = (short)f2bf_fast(a.w);
  r[4] = (short)f2bf_fast(b.x); r[5] = (short)f2bf_fast(b.y);
  r[6] = (short)f2bf_fast(b.z); r[7] = (short)f2bf_fast(b.w);
  return r;
}

// async global->LDS, 16B/lane. ldsptr must be WAVE-UNIFORM (HW adds lane*16);
// gptr is per-lane. Drained by __syncthreads (vmcnt(0) before s_barrier).
static __device__ __forceinline__ void async_ld16(const void* g, void* l) {
  __builtin_amdgcn_global_load_lds(
      (const __attribute__((address_space(1))) unsigned int*)g,
      (__attribute__((address_space(3))) unsigned int*)l, 16, 0, 0);
}

// DPP-based max over each 16-lane group (all lanes receive the result).
template <int CTRL>
static __device__ __forceinline__ float fmax_dpp(float x) {
  int t = __builtin_amdgcn_update_dpp(__float_as_int(x), __float_as_int(x),
                                      CTRL, 0xF, 0xF, true);
  return fmaxf(x, __int_as_float(t));
}
static __device__ __forceinline__ float max16_dpp(float x) {
  x = fmax_dpp<0xB1>(x);   // quad_perm xor1
  x = fmax_dpp<0x4E>(x);   // quad_perm xor2
  x = fmax_dpp<0x141>(x);  // row_half_mirror
  x = fmax_dpp<0x140>(x);  // row_mirror
  return x;
}

// ---------------------------------------------------------------------------
// weights fp32 -> bf16 (4 x 768x768). grid (576, 4), 256 thr.
// ---------------------------------------------------------------------------
__global__ __launch_bounds__(256) void cvt_w4(
    const float* __restrict__ w0, const float* __restrict__ w1,
    const float* __restrict__ w2, const float* __restrict__ w3,
    unsigned short* __restrict__ o)
{
  const int z = blockIdx.y;
  const float* src = (z == 0) ? w0 : (z == 1) ? w1 : (z == 2) ? w2 : w3;
  unsigned short* dst = o + (size_t)z * 589824;
  const int i = blockIdx.x * 256 + threadIdx.x;  // exact: 576*256 = 147456
  float4 f = ((const float4*)src)[i];
  ushort4v v;
  v[0] = f2bf_fast(f.x); v[1] = f2bf_fast(f.y);
  v[2] = f2bf_fast(f.z); v[3] = f2bf_fast(f.w);
  ((ushort4v*)dst)[i] = v;
}

// ---------------------------------------------------------------------------
// 128x128-tile GEMM. bf16 operands staged via global_load_lds width-16
// (m97 lever): LDS dest linear (wave-uniform base, HW adds lane*16),
// per-lane global src row = wave*32 + i*16 + lane/4, chunk = (lane&3)*8.
// fp32 A (XF32=1) keeps the register cvt path.
// ---------------------------------------------------------------------------
template<int XF32, int OUTF32>
__device__ __forceinline__ void gemm128(
    const void* Xp, const unsigned short* Wb, const float* bias,
    void* outp, float scale, int vt_mode, int bm, int bn)
{
  __shared__ unsigned short Als[128 * 32];
  __shared__ unsigned short Bls[128 * 32];

  const int tid = threadIdx.x;
  const int wave = tid >> 6, lane = tid & 63;
  const int g = lane >> 4, lo = lane & 15;
  const int wr = wave >> 1, wc = wave & 1;
  const int m0 = bm * 128, n0 = bn * 128;

  const f32x4 vzero = {0.f, 0.f, 0.f, 0.f};
  f32x4 acc[4][4];
#pragma unroll
  for (int m = 0; m < 4; ++m)
#pragma unroll
    for (int n = 0; n < 4; ++n) acc[m][n] = vzero;

  // fp32-A register-path addressing (XF32=1 only)
  const int arow = tid >> 1;        // 0..127
  const int acol = (tid & 1) * 16;  // 0 or 16
  const float* Af = nullptr;
  if constexpr (XF32) Af = (const float*)Xp + (size_t)(m0 + arow) * 768 + acol;

  // async-path addressing (B always; A when bf16)
  const int ldrow = wave * 32 + (lane >> 2);   // +16 for the second instr
  const int ldc = (lane & 3) * 8;
  const unsigned short* bsrc0 = Wb + (size_t)(n0 + ldrow) * 768 + ldc;
  const unsigned short* bsrc1 = bsrc0 + (size_t)16 * 768;
  char* const bdst0 = (char*)Bls + (wave * 2) * 1024;      // wave-uniform
  char* const bdst1 = bdst0 + 1024;
  const unsigned short* asrc0 = nullptr;
  const unsigned short* asrc1 = nullptr;
  if constexpr (!XF32) {
    asrc0 = (const unsigned short*)Xp + (size_t)(m0 + ldrow) * 768 + ldc;
    asrc1 = asrc0 + (size_t)16 * 768;
  }
  char* const adst0 = (char*)Als + (wave * 2) * 1024;
  char* const adst1 = adst0 + 1024;

  for (int k0 = 0; k0 < 768; k0 += 32) {
    short8 va0, va1;
    if constexpr (XF32) {  // prefetched vs prev tile's mfma
      float4 f0 = *(const float4*)(Af + k0);
      float4 f1 = *(const float4*)(Af + k0 + 4);
      float4 f2 = *(const float4*)(Af + k0 + 8);
      float4 f3 = *(const float4*)(Af + k0 + 12);
      va0 = pack8(f0, f1);
      va1 = pack8(f2, f3);
    }

    __syncthreads();  // previous tile fully consumed (WAR)
    if constexpr (XF32) {
      *(short8*)(Als + arow * 32 + acol)     = va0;
      *(short8*)(Als + arow * 32 + acol + 8) = va1;
    } else {
      async_ld16(asrc0 + k0, adst0);
      async_ld16(asrc1 + k0, adst1);
    }
    async_ld16(bsrc0 + k0, bdst0);
    async_ld16(bsrc1 + k0, bdst1);
    __syncthreads();  // drains vmcnt+lgkmcnt -> tile visible

    short8 af[4], bf[4];
#pragma unroll
    for (int m = 0; m < 4; ++m)
      af[m] = *(const short8*)(Als + (wr * 64 + m * 16 + lo) * 32 + g * 8);
#pragma unroll
    for (int n = 0; n < 4; ++n)
      bf[n] = *(const short8*)(Bls + (wc * 64 + n * 16 + lo) * 32 + g * 8);
#pragma unroll
    for (int m = 0; m < 4; ++m)
#pragma unroll
      for (int n = 0; n < 4; ++n)
        acc[m][n] = __builtin_amdgcn_mfma_f32_16x16x32_bf16(af[m], bf[n], acc[m][n], 0, 0, 0);
  }

#pragma unroll
  for (int n = 0; n < 4; ++n) {
    const int ncol = n0 + wc * 64 + n * 16 + lo;
    const float bb = bias[ncol];
#pragma unroll
    for (int m = 0; m < 4; ++m) {
      const int rowb = m0 + wr * 64 + m * 16 + g * 4;
      if constexpr (OUTF32) {
        float* out = (float*)outp;
#pragma unroll
        for (int r = 0; r < 4; ++r)
          out[(size_t)(rowb + r) * 768 + ncol] = (acc[m][n][r] + bb) * scale;
      } else {
        unsigned short* out = (unsigned short*)outp;
        if (!vt_mode) {
#pragma unroll
          for (int r = 0; r < 4; ++r)
            out[(size_t)(rowb + r) * 768 + ncol] = f2bf((acc[m][n][r] + bb) * scale);
        } else {
          const int b = rowb >> 12, s = rowb & 4095;
          const int hh = ncol >> 6, d = ncol & 63;
          ushort4v pk;
#pragma unroll
          for (int r = 0; r < 4; ++r) pk[r] = f2bf((acc[m][n][r] + bb) * scale);
          *(ushort4v*)(out + (((size_t)b * 12 + hh) * 64 + d) * 4096 + s) = pk;
        }
      }
    }
  }
}

__global__ __launch_bounds__(256, 2) void qkv_proj(
    const float* __restrict__ Qi, const float* __restrict__ Ki,
    const float* __restrict__ Vi,
    const unsigned short* __restrict__ Wq, const float* __restrict__ bq,
    const unsigned short* __restrict__ Wk, const float* __restrict__ bk,
    const unsigned short* __restrict__ Wv, const float* __restrict__ bv,
    unsigned short* __restrict__ qo, unsigned short* __restrict__ ko,
    unsigned short* __restrict__ vto)
{
  const int z = blockIdx.z;
  const float* X = (z == 0) ? Qi : (z == 1) ? Ki : Vi;
  const unsigned short* W = (z == 0) ? Wq : (z == 1) ? Wk : Wv;
  const float* bb = (z == 0) ? bq : (z == 1) ? bk : bv;
  unsigned short* out = (z == 0) ? qo : (z == 1) ? ko : vto;
  // q gets 1/sqrt(dk) * log2(e) so softmax runs in exp2 domain
  const float scale = (z == 0) ? 0.18033688011f : 1.0f;
  gemm128<1, 0>(X, W, bb, out, scale, (z == 2) ? 1 : 0, blockIdx.x, blockIdx.y);
}

__global__ __launch_bounds__(256, 2) void out_proj(
    const unsigned short* __restrict__ X, const unsigned short* __restrict__ W,
    const float* __restrict__ bias, float* __restrict__ out)
{
  gemm128<0, 1>(X, W, bias, out, 1.0f, 0, blockIdx.x, blockIdx.y);
}

// ---------------------------------------------------------------------------
// Flash attention (r18 verbatim — V staging restored; r19's V-from-global
// thrashed L2: 16 heads x 512KB live per 4MB XCD-L2, FETCH 104MB -> 1.36GB).
// q [8192][768] (pre-scaled by 0.125*log2e, bf16), k bf16, vt [B][H][64][4096]
// bf16. O in-place into qw. grid (32,24), 512 thr (8 waves), 16 q-rows/wave.
// ---------------------------------------------------------------------------
__global__ __launch_bounds__(512, 6) void attn_fwd(
    const unsigned short* qw, const unsigned short* __restrict__ kw,
    const unsigned short* __restrict__ vtw, unsigned short* ow)
{
  __shared__ unsigned short Kls[64 * 64];
  __shared__ unsigned short Vls[64 * 64];
  __shared__ unsigned short Pls[8 * 16 * 72];  // per-wave [16][72]

  const int tid = threadIdx.x, wave = tid >> 6, lane = tid & 63;
  const int g = lane >> 4, lo = lane & 15;
  const int bh = blockIdx.y, b = bh / 12, hh = bh % 12;
  const int q0 = blockIdx.x * 128 + wave * 16;

  // Q A-fragments: rows q0+lo, k-dims s*32+g*8..+7
  short8 aq[2];
#pragma unroll
  for (int s = 0; s < 2; ++s)
    aq[s] = *(const short8*)(qw + (size_t)(b * 4096 + q0 + lo) * 768
                             + hh * 64 + s * 32 + g * 8);

  const f32x4 vzero = {0.f, 0.f, 0.f, 0.f};
  float mx[4];
  f32x4 lacc = vzero;   // row-sum accumulator via ones-MFMA
  f32x4 oacc[4];
#pragma unroll
  for (int r = 0; r < 4; ++r) mx[r] = -1e30f;
#pragma unroll
  for (int n = 0; n < 4; ++n) oacc[n] = vzero;

  short8 bone;  // B-fragment of bf16 1.0 -> D[row][*] = row-sum of A
#pragma unroll
  for (int j = 0; j < 8; ++j) bone[j] = (short)0x3F80;

  unsigned short* Pw = Pls + wave * (16 * 72);
  char* Kb = (char*)Kls;
  char* Vb = (char*)Vls;

  // staging: 512 threads cover 64 rows x 8 x 16B chunks (1 chunk each)
  const int srow = tid >> 3;
  const int sc = tid & 7;
  const unsigned short* krow = kw + ((size_t)b * 4096 + srow) * 768 + hh * 64 + sc * 8;
  const unsigned short* vrow = vtw + ((size_t)bh * 64 + srow) * 4096 + sc * 8;
  const int sdst = srow * 128 + ((sc * 16) ^ ((srow & 7) << 4));

  // prefetch tile 0
  short8 kl = *(const short8*)(krow);
  short8 vl = *(const short8*)(vrow);

  for (int kv0 = 0; kv0 < 4096; kv0 += 64) {
    // WAR: all waves done reading previous tile's LDS. Raw barrier: does NOT
    // drain vmcnt, so the prefetched loads stay in flight.
    asm volatile("s_waitcnt lgkmcnt(0)" ::: "memory");
    __builtin_amdgcn_s_barrier();
    *(short8*)(Kb + sdst) = kl;   // compiler inserts vmcnt wait (data dep)
    *(short8*)(Vb + sdst) = vl;
    if (kv0 + 64 < 4096) {        // prefetch next tile (in flight over compute)
      kl = *(const short8*)(krow + (size_t)(kv0 + 64) * 768);
      vl = *(const short8*)(vrow + (kv0 + 64));
    }
    asm volatile("s_waitcnt lgkmcnt(0)" ::: "memory");  // my writes visible
    __builtin_amdgcn_s_barrier();                       // all writes visible
    __builtin_amdgcn_sched_barrier(0);                  // pin: no hoist above

    // ---- S = q @ k^T (exp2-domain scale folded into q) ----
    f32x4 sa[4];
#pragma unroll
    for (int n = 0; n < 4; ++n) {
      const int row = n * 16 + lo;
      const int rsw = (row & 7) << 4;
      short8 bk0 = *(const short8*)(Kb + row * 128 + ((g * 16) ^ rsw));
      short8 bk1 = *(const short8*)(Kb + row * 128 + ((64 + g * 16) ^ rsw));
      f32x4 t = vzero;
      t = __builtin_amdgcn_mfma_f32_16x16x32_bf16(aq[0], bk0, t, 0, 0, 0);
      t = __builtin_amdgcn_mfma_f32_16x16x32_bf16(aq[1], bk1, t, 0, 0, 0);
      sa[n] = t;
    }

    // ---- online softmax (row = g*4 + r, cols = n*16 + lo) ----
#pragma unroll
    for (int r = 0; r < 4; ++r) {
      float pm = fmaxf(fmaxf(sa[0][r], sa[1][r]), fmaxf(sa[2][r], sa[3][r]));
      pm = max16_dpp(pm);
      if (pm > mx[r] + 8.f) {  // defer-max: rescale only on big max growth
        const float fr = __builtin_amdgcn_exp2f(mx[r] - pm);  // 1st tile: 0
        mx[r] = pm;
        lacc[r] *= fr;
#pragma unroll
        for (int nd = 0; nd < 4; ++nd) oacc[nd][r] *= fr;
      }
#pragma unroll
      for (int n = 0; n < 4; ++n) {
        const float pv = __builtin_amdgcn_exp2f(sa[n][r] - mx[r]);
        // truncating bf16 store: fuses to ds_write_b16_d16_hi (0 VALU rounding)
        *(unsigned short*)((char*)Pw + (g * 4 + r) * 144 + n * 32 + lo * 2) =
            (unsigned short)(__float_as_uint(pv) >> 16);
      }
    }

    // ---- O += P @ V ; l += P @ 1 ----
    short8 ap0 = *(const short8*)((char*)Pw + lo * 144 + g * 16);
    short8 ap1 = *(const short8*)((char*)Pw + lo * 144 + 64 + g * 16);
#pragma unroll
    for (int nd = 0; nd < 4; ++nd) {
      const int row = nd * 16 + lo;
      const int rsw = (row & 7) << 4;
      short8 bv0 = *(const short8*)(Vb + row * 128 + ((g * 16) ^ rsw));
      short8 bv1 = *(const short8*)(Vb + row * 128 + ((64 + g * 16) ^ rsw));
      oacc[nd] = __builtin_amdgcn_mfma_f32_16x16x32_bf16(ap0, bv0, oacc[nd], 0, 0, 0);
      oacc[nd] = __builtin_amdgcn_mfma_f32_16x16x32_bf16(ap1, bv1, oacc[nd], 0, 0, 0);
    }
    lacc = __builtin_amdgcn_mfma_f32_16x16x32_bf16(ap0, bone, lacc, 0, 0, 0);
    lacc = __builtin_amdgcn_mfma_f32_16x16x32_bf16(ap1, bone, lacc, 0, 0, 0);
  }

  // epilogue: normalize (RNE), store merged-head bf16 [8192][768] (in-place ok)
#pragma unroll
  for (int r = 0; r < 4; ++r) {
    const float inv = 1.f / lacc[r];
    const size_t rowoff = (size_t)(b * 4096 + q0 + g * 4 + r) * 768 + hh * 64;
#pragma unroll
    for (int nd = 0; nd < 4; ++nd)
      ow[rowoff + nd * 16 + lo] = f2bf(oacc[nd][r] * inv);
  }
}

extern "C" void kernel_launch(void* const* d_in, const int* in_sizes, int n_in,
                              void* d_out, int out_size, void* d_ws, size_t ws_size,
                              hipStream_t stream) {
  (void)in_sizes; (void)n_in; (void)out_size; (void)ws_size;
  const float* Qi = (const float*)d_in[0];
  const float* Ki = (const float*)d_in[1];
  const float* Vi = (const float*)d_in[2];
  const float* Wq = (const float*)d_in[3];
  const float* bq = (const float*)d_in[4];
  const float* Wk = (const float*)d_in[5];
  const float* bk = (const float*)d_in[6];
  const float* Wv = (const float*)d_in[7];
  const float* bv = (const float*)d_in[8];
  const float* Wo = (const float*)d_in[9];
  const float* bo = (const float*)d_in[10];

  // ws: q bf16 + v^T bf16 (25.2 MB) + 4 bf16 weights (4.7 MB).
  // k bf16 scratch lives in d_out's first 12.6 MB (overwritten by out_proj's
  // fp32 output at the very end, stream-ordered). Attn output in-place in qw.
  unsigned short* ws = (unsigned short*)d_ws;
  const size_t NTOK = 8192u * 768u;  // 6291456
  const size_t NW = 589824;          // 768*768
  unsigned short* qw  = ws;
  unsigned short* vtw = ws + NTOK;
  unsigned short* wbf = ws + 2 * NTOK;
  unsigned short* Wqc = wbf;
  unsigned short* Wkc = wbf + NW;
  unsigned short* Wvc = wbf + 2 * NW;
  unsigned short* Woc = wbf + 3 * NW;
  unsigned short* kwp = (unsigned short*)d_out;

  cvt_w4<<<dim3(576, 4), 256, 0, stream>>>(Wq, Wk, Wv, Wo, wbf);
  qkv_proj<<<dim3(64, 6, 3), 256, 0, stream>>>(Qi, Ki, Vi, Wqc, bq, Wkc, bk,
                                               Wvc, bv, qw, kwp, vtw);
  attn_fwd<<<dim3(32, 24, 1), 512, 0, stream>>>(qw, kwp, vtw, qw);
  out_proj<<<dim3(64, 6, 1), 256, 0, stream>>>(qw, Woc, bo, (float*)d_out);
}